// Round 5
// baseline (127.897 us; speedup 1.0000x reference)
//
#include <hip/hip_runtime.h>
#include <cstdint>
#include <cstddef>

#define BATCH 8
#define SEQ 1024
#define DIM 768
#define EPS_K 1e-7f

typedef __bf16 bf16x8 __attribute__((ext_vector_type(8)));
typedef float f32x4 __attribute__((ext_vector_type(4)));
typedef uint16_t u16x8 __attribute__((ext_vector_type(8)));

#define MFMA(a, b, c) __builtin_amdgcn_mfma_f32_16x16x32_bf16((a), (b), (c), 0, 0, 0)

__device__ __forceinline__ uint16_t f2bf(float f) {
  union { float f; uint32_t u; } v; v.f = f;
  uint32_t u = v.u;
  u += 0x7FFFu + ((u >> 16) & 1u);   // RNE to bf16
  return (uint16_t)(u >> 16);
}

__device__ __forceinline__ void gload16(const void* g, void* l) {
  __builtin_amdgcn_global_load_lds(
      (const __attribute__((address_space(1))) uint32_t*)g,
      (__attribute__((address_space(3))) uint32_t*)l, 16, 0, 0);
}

// ---------------------------------------------------------------------------
// Kernel 1: fp32 -> bf16 convert: ab[b][s][d] row-major, at[b][d][s] transposed
// ---------------------------------------------------------------------------
__global__ __launch_bounds__(256) void convert_kernel(const float* __restrict__ A,
                                                      uint16_t* __restrict__ ab,
                                                      uint16_t* __restrict__ at) {
  const int b  = blockIdx.z;
  const int s0 = blockIdx.y * 64;
  const int d0 = blockIdx.x * 64;
  __shared__ uint16_t tl[64][80];
  const int tid = threadIdx.x;
#pragma unroll
  for (int i = 0; i < 2; ++i) {
    const int sl = (tid >> 3) + i * 32;
    const int ch = tid & 7;
    const float* src = A + ((size_t)b * SEQ + s0 + sl) * DIM + d0 + ch * 8;
    float4 f0 = *(const float4*)src;
    float4 f1 = *(const float4*)(src + 4);
    u16x8 h;
    h[0] = f2bf(f0.x); h[1] = f2bf(f0.y); h[2] = f2bf(f0.z); h[3] = f2bf(f0.w);
    h[4] = f2bf(f1.x); h[5] = f2bf(f1.y); h[6] = f2bf(f1.z); h[7] = f2bf(f1.w);
    *(u16x8*)&ab[((size_t)b * SEQ + s0 + sl) * DIM + d0 + ch * 8] = h;
    *(u16x8*)&tl[sl][ch * 8] = h;
  }
  __syncthreads();
  const int dl = tid >> 2;
#pragma unroll
  for (int i = 0; i < 2; ++i) {
    const int sc = (tid & 3) + i * 4;
    u16x8 h;
#pragma unroll
    for (int e = 0; e < 8; ++e) h[e] = tl[sc * 8 + e][dl];
    *(u16x8*)&at[((size_t)b * DIM + d0 + dl) * SEQ + s0 + sc * 8] = h;
  }
}

// ---------------------------------------------------------------------------
// Shared geometry (kernels 2 & 3): BM=256, BN=128, BK=64, 8 waves (4M x 2N),
// per-wave out 64x64 (4x4 frags). LDS 96KB. T2 both-sides swizzle (verified).
// K-loop: 4-phase fine interleave, counted vmcnt(2), 5 barriers/iter (T3+T4),
// setprio around each 8-MFMA cluster (T5).
// ---------------------------------------------------------------------------

// Kernel 2: P[b][q][t] = m_q*m_t*exp(ab[q]·ab[t])  (bf16)
__global__ __launch_bounds__(512, 2) void scores_kernel(const uint16_t* __restrict__ ab,
                                                        const int* __restrict__ mask,
                                                        uint16_t* __restrict__ P) {
  const int b    = blockIdx.x & 7;
  const int tile = blockIdx.x >> 3;          // 0..31
  const int s0   = (tile >> 3) * 256;
  const int t0   = (tile & 7) * 128;

  const int tid  = threadIdx.x;
  const int lane = tid & 63;
  const int wid  = tid >> 6;
  const int wr   = wid >> 1;                 // 0..3
  const int wc   = wid & 1;                  // 0..1

  __shared__ __align__(16) uint16_t lA[2][256 * 64];
  __shared__ __align__(16) uint16_t lB[2][128 * 64];

  const uint16_t* gA = ab + ((size_t)b * SEQ + s0) * DIM;
  const uint16_t* gB = ab + ((size_t)b * SEQ + t0) * DIM;

  const int srl  = tid >> 3;
  const int schx = ((tid & 7) ^ (srl & 7)) << 3;
  const int sdst = srl * 64 + (tid & 7) * 8;

#define STAGE_A2(buf, k0, h)                                                   \
  { gload16(gA + (size_t)(srl + (2*(h)) * 64) * DIM + (k0) + schx,             \
            &lA[buf][sdst + (2*(h)) * 4096]);                                  \
    gload16(gA + (size_t)(srl + (2*(h)+1) * 64) * DIM + (k0) + schx,           \
            &lA[buf][sdst + (2*(h)+1) * 4096]); }
#define STAGE_B1(buf, k0, h)                                                   \
  gload16(gB + (size_t)(srl + (h) * 64) * DIM + (k0) + schx,                   \
          &lB[buf][sdst + (h) * 4096]);

  f32x4 acc[4][4];
#pragma unroll
  for (int m = 0; m < 4; ++m)
#pragma unroll
    for (int n = 0; n < 4; ++n) acc[m][n] = f32x4{0.f, 0.f, 0.f, 0.f};

  const int rA  = wr * 64 + (lane & 15);
  const int rB  = wc * 64 + (lane & 15);
  const int cx0 = (((lane >> 4) + 0) ^ (lane & 7)) << 3;
  const int cx1 = (((lane >> 4) + 4) ^ (lane & 7)) << 3;

  // prologue: stage tile 0 fully
  STAGE_A2(0, 0, 0); STAGE_A2(0, 0, 1); STAGE_B1(0, 0, 0); STAGE_B1(0, 0, 1);

  const int NT = DIM / 64;                   // 12
  int cur = 0;
  for (int t = 0; t < NT; ++t) {
    const int k0n = (t + 1) * 64;
    const bool pf = (t + 1 < NT);
    const int nx = cur ^ 1;
    if (pf) { STAGE_A2(nx, k0n, 0); asm volatile("s_waitcnt vmcnt(2)" ::: "memory"); }
    else    {                        asm volatile("s_waitcnt vmcnt(0)" ::: "memory"); }
    __builtin_amdgcn_s_barrier();            // publish tile t

    bf16x8 bq[4], alo, ahi;
    // ---- ph0: B kk0 + A m0,m1 kk0 ; stage Ah1 ; 8 MFMA
#pragma unroll
    for (int n = 0; n < 4; ++n) bq[n] = *(const bf16x8*)&lB[cur][(rB + n * 16) * 64 + cx0];
    alo = *(const bf16x8*)&lA[cur][(rA + 0) * 64 + cx0];
    ahi = *(const bf16x8*)&lA[cur][(rA + 16) * 64 + cx0];
    if (pf) STAGE_A2(nx, k0n, 1);
    __builtin_amdgcn_s_setprio(1);
#pragma unroll
    for (int n = 0; n < 4; ++n) { acc[0][n] = MFMA(alo, bq[n], acc[0][n]); acc[1][n] = MFMA(ahi, bq[n], acc[1][n]); }
    __builtin_amdgcn_s_setprio(0);
    __builtin_amdgcn_s_barrier();
    // ---- ph1: A m2,m3 kk0 ; stage Bh0 ; 8 MFMA
    alo = *(const bf16x8*)&lA[cur][(rA + 32) * 64 + cx0];
    ahi = *(const bf16x8*)&lA[cur][(rA + 48) * 64 + cx0];
    if (pf) STAGE_B1(nx, k0n, 0);
    __builtin_amdgcn_s_setprio(1);
#pragma unroll
    for (int n = 0; n < 4; ++n) { acc[2][n] = MFMA(alo, bq[n], acc[2][n]); acc[3][n] = MFMA(ahi, bq[n], acc[3][n]); }
    __builtin_amdgcn_s_setprio(0);
    __builtin_amdgcn_s_barrier();
    // ---- ph2: B kk1 + A m0,m1 kk1 ; stage Bh1 ; 8 MFMA
#pragma unroll
    for (int n = 0; n < 4; ++n) bq[n] = *(const bf16x8*)&lB[cur][(rB + n * 16) * 64 + cx1];
    alo = *(const bf16x8*)&lA[cur][(rA + 0) * 64 + cx1];
    ahi = *(const bf16x8*)&lA[cur][(rA + 16) * 64 + cx1];
    if (pf) STAGE_B1(nx, k0n, 1);
    __builtin_amdgcn_s_setprio(1);
#pragma unroll
    for (int n = 0; n < 4; ++n) { acc[0][n] = MFMA(alo, bq[n], acc[0][n]); acc[1][n] = MFMA(ahi, bq[n], acc[1][n]); }
    __builtin_amdgcn_s_setprio(0);
    __builtin_amdgcn_s_barrier();
    // ---- ph3: A m2,m3 kk1 ; 8 MFMA
    alo = *(const bf16x8*)&lA[cur][(rA + 32) * 64 + cx1];
    ahi = *(const bf16x8*)&lA[cur][(rA + 48) * 64 + cx1];
    __builtin_amdgcn_s_setprio(1);
#pragma unroll
    for (int n = 0; n < 4; ++n) { acc[2][n] = MFMA(alo, bq[n], acc[2][n]); acc[3][n] = MFMA(ahi, bq[n], acc[3][n]); }
    __builtin_amdgcn_s_setprio(0);
    __builtin_amdgcn_s_barrier();            // WAR fence for next iter's stage
    cur ^= 1;
  }
#undef STAGE_A2
#undef STAGE_B1

  // Epilogue: e = exp(S)*m_q*m_t, bf16 store.
  const int* mk = mask + b * SEQ;
  uint16_t* Pb = P + (size_t)b * SEQ * SEQ;
  float mc[4];
#pragma unroll
  for (int n = 0; n < 4; ++n) mc[n] = (float)mk[t0 + wc * 64 + n * 16 + (lane & 15)];
#pragma unroll
  for (int m = 0; m < 4; ++m) {
#pragma unroll
    for (int j = 0; j < 4; ++j) {
      const int rs = s0 + wr * 64 + m * 16 + (lane >> 4) * 4 + j;
      const float mr = (float)mk[rs];
#pragma unroll
      for (int n = 0; n < 4; ++n) {
        const int ct = t0 + wc * 64 + n * 16 + (lane & 15);
        float e = __expf(acc[m][n][j]) * mr * mc[n];
        Pb[(size_t)rs * SEQ + ct] = f2bf(e);
      }
    }
  }
}

// Kernel 3: out[b][q][d] = sum_t P[q][t]*at[d][t] / (den_q+eps); den via ones-MFMA
__global__ __launch_bounds__(512, 2) void out_kernel(const uint16_t* __restrict__ P,
                                                     const uint16_t* __restrict__ at,
                                                     float* __restrict__ out) {
  const int b    = blockIdx.x & 7;
  const int tile = blockIdx.x >> 3;          // 0..23
  const int q0   = (tile / 6) * 256;
  const int d0   = (tile % 6) * 128;

  const int tid  = threadIdx.x;
  const int lane = tid & 63;
  const int wid  = tid >> 6;
  const int wr   = wid >> 1;
  const int wc   = wid & 1;

  __shared__ __align__(16) uint16_t lA[2][256 * 64];
  __shared__ __align__(16) uint16_t lB[2][128 * 64];

  const uint16_t* gA = P  + ((size_t)b * SEQ + q0) * SEQ;
  const uint16_t* gB = at + ((size_t)b * DIM + d0) * SEQ;

  const int srl  = tid >> 3;
  const int schx = ((tid & 7) ^ (srl & 7)) << 3;
  const int sdst = srl * 64 + (tid & 7) * 8;

#define STAGE_A2(buf, k0, h)                                                   \
  { gload16(gA + (size_t)(srl + (2*(h)) * 64) * SEQ + (k0) + schx,             \
            &lA[buf][sdst + (2*(h)) * 4096]);                                  \
    gload16(gA + (size_t)(srl + (2*(h)+1) * 64) * SEQ + (k0) + schx,           \
            &lA[buf][sdst + (2*(h)+1) * 4096]); }
#define STAGE_B1(buf, k0, h)                                                   \
  gload16(gB + (size_t)(srl + (h) * 64) * SEQ + (k0) + schx,                   \
          &lB[buf][sdst + (h) * 4096]);

  f32x4 acc[4][4];
  f32x4 accd[4];
#pragma unroll
  for (int m = 0; m < 4; ++m) {
    accd[m] = f32x4{0.f, 0.f, 0.f, 0.f};
#pragma unroll
    for (int n = 0; n < 4; ++n) acc[m][n] = f32x4{0.f, 0.f, 0.f, 0.f};
  }
  bf16x8 ones;
#pragma unroll
  for (int i = 0; i < 8; ++i) ones[i] = (__bf16)1.0f;

  const int rA  = wr * 64 + (lane & 15);
  const int rB  = wc * 64 + (lane & 15);
  const int cx0 = (((lane >> 4) + 0) ^ (lane & 7)) << 3;
  const int cx1 = (((lane >> 4) + 4) ^ (lane & 7)) << 3;

  STAGE_A2(0, 0, 0); STAGE_A2(0, 0, 1); STAGE_B1(0, 0, 0); STAGE_B1(0, 0, 1);

  const int NT = SEQ / 64;                   // 16
  int cur = 0;
  for (int t = 0; t < NT; ++t) {
    const int k0n = (t + 1) * 64;
    const bool pf = (t + 1 < NT);
    const int nx = cur ^ 1;
    if (pf) { STAGE_A2(nx, k0n, 0); asm volatile("s_waitcnt vmcnt(2)" ::: "memory"); }
    else    {                        asm volatile("s_waitcnt vmcnt(0)" ::: "memory"); }
    __builtin_amdgcn_s_barrier();

    bf16x8 bq[4], alo, ahi;
    // ph0
#pragma unroll
    for (int n = 0; n < 4; ++n) bq[n] = *(const bf16x8*)&lB[cur][(rB + n * 16) * 64 + cx0];
    alo = *(const bf16x8*)&lA[cur][(rA + 0) * 64 + cx0];
    ahi = *(const bf16x8*)&lA[cur][(rA + 16) * 64 + cx0];
    if (pf) STAGE_A2(nx, k0n, 1);
    __builtin_amdgcn_s_setprio(1);
#pragma unroll
    for (int n = 0; n < 4; ++n) { acc[0][n] = MFMA(alo, bq[n], acc[0][n]); acc[1][n] = MFMA(ahi, bq[n], acc[1][n]); }
    accd[0] = MFMA(alo, ones, accd[0]); accd[1] = MFMA(ahi, ones, accd[1]);
    __builtin_amdgcn_s_setprio(0);
    __builtin_amdgcn_s_barrier();
    // ph1
    alo = *(const bf16x8*)&lA[cur][(rA + 32) * 64 + cx0];
    ahi = *(const bf16x8*)&lA[cur][(rA + 48) * 64 + cx0];
    if (pf) STAGE_B1(nx, k0n, 0);
    __builtin_amdgcn_s_setprio(1);
#pragma unroll
    for (int n = 0; n < 4; ++n) { acc[2][n] = MFMA(alo, bq[n], acc[2][n]); acc[3][n] = MFMA(ahi, bq[n], acc[3][n]); }
    accd[2] = MFMA(alo, ones, accd[2]); accd[3] = MFMA(ahi, ones, accd[3]);
    __builtin_amdgcn_s_setprio(0);
    __builtin_amdgcn_s_barrier();
    // ph2
#pragma unroll
    for (int n = 0; n < 4; ++n) bq[n] = *(const bf16x8*)&lB[cur][(rB + n * 16) * 64 + cx1];
    alo = *(const bf16x8*)&lA[cur][(rA + 0) * 64 + cx1];
    ahi = *(const bf16x8*)&lA[cur][(rA + 16) * 64 + cx1];
    if (pf) STAGE_B1(nx, k0n, 1);
    __builtin_amdgcn_s_setprio(1);
#pragma unroll
    for (int n = 0; n < 4; ++n) { acc[0][n] = MFMA(alo, bq[n], acc[0][n]); acc[1][n] = MFMA(ahi, bq[n], acc[1][n]); }
    accd[0] = MFMA(alo, ones, accd[0]); accd[1] = MFMA(ahi, ones, accd[1]);
    __builtin_amdgcn_s_setprio(0);
    __builtin_amdgcn_s_barrier();
    // ph3
    alo = *(const bf16x8*)&lA[cur][(rA + 32) * 64 + cx1];
    ahi = *(const bf16x8*)&lA[cur][(rA + 48) * 64 + cx1];
    __builtin_amdgcn_s_setprio(1);
#pragma unroll
    for (int n = 0; n < 4; ++n) { acc[2][n] = MFMA(alo, bq[n], acc[2][n]); acc[3][n] = MFMA(ahi, bq[n], acc[3][n]); }
    accd[2] = MFMA(alo, ones, accd[2]); accd[3] = MFMA(ahi, ones, accd[3]);
    __builtin_amdgcn_s_setprio(0);
    __builtin_amdgcn_s_barrier();
    cur ^= 1;
  }
#undef STAGE_A2
#undef STAGE_B1

  float* ob = out + (size_t)b * SEQ * DIM;
#pragma unroll
  for (int m = 0; m < 4; ++m) {
#pragma unroll
    for (int j = 0; j < 4; ++j) {
      const int q  = q0 + wr * 64 + m * 16 + (lane >> 4) * 4 + j;
      const float sc = 1.0f / (accd[m][j] + EPS_K);
#pragma unroll
      for (int n = 0; n < 4; ++n) {
        const int d = d0 + wc * 64 + n * 16 + (lane & 15);
        ob[(size_t)q * DIM + d] = acc[m][n][j] * sc;
      }
    }
  }
}

// ---------------------------------------------------------------------------
extern "C" void kernel_launch(void* const* d_in, const int* in_sizes, int n_in,
                              void* d_out, int out_size, void* d_ws, size_t ws_size,
                              hipStream_t stream) {
  (void)in_sizes; (void)n_in; (void)out_size; (void)ws_size;
  const float* A    = (const float*)d_in[0];
  const int*   mask = (const int*)d_in[1];
  float*       out  = (float*)d_out;

  char* ws = (char*)d_ws;
  const size_t NB_AB = (size_t)BATCH * SEQ * DIM * 2;
  const size_t NB_AT = NB_AB;
  uint16_t* ab = (uint16_t*)(ws);
  uint16_t* at = (uint16_t*)(ws + NB_AB);
  uint16_t* P  = (uint16_t*)(ws + NB_AB + NB_AT);

  convert_kernel<<<dim3(DIM / 64, SEQ / 64, BATCH), dim3(256), 0, stream>>>(A, ab, at);
  scores_kernel<<<dim3(32 * BATCH), dim3(512), 0, stream>>>(ab, mask, P);
  out_kernel<<<dim3(24 * BATCH), dim3(512), 0, stream>>>(P, at, out);
}

// Round 6
// 126.708 us; speedup vs baseline: 1.0094x; 1.0094x over previous
//
#include <hip/hip_runtime.h>
#include <cstdint>
#include <cstddef>

#define BATCH 8
#define SEQ 1024
#define DIM 768
#define EPS_K 1e-7f

typedef __bf16 bf16x8 __attribute__((ext_vector_type(8)));
typedef float f32x16 __attribute__((ext_vector_type(16)));
typedef uint16_t u16x8 __attribute__((ext_vector_type(8)));

#define MFMA32(a, b, c) __builtin_amdgcn_mfma_f32_32x32x16_bf16((a), (b), (c), 0, 0, 0)

__device__ __forceinline__ uint16_t f2bf(float f) {
  union { float f; uint32_t u; } v; v.f = f;
  uint32_t u = v.u;
  u += 0x7FFFu + ((u >> 16) & 1u);   // RNE to bf16
  return (uint16_t)(u >> 16);
}

__device__ __forceinline__ void gload16(const void* g, void* l) {
  __builtin_amdgcn_global_load_lds(
      (const __attribute__((address_space(1))) uint32_t*)g,
      (__attribute__((address_space(3))) uint32_t*)l, 16, 0, 0);
}

// ---------------------------------------------------------------------------
// Kernel 1: fp32 -> bf16 convert: ab[b][s][d] row-major, at[b][d][s] transposed
// ---------------------------------------------------------------------------
__global__ __launch_bounds__(256) void convert_kernel(const float* __restrict__ A,
                                                      uint16_t* __restrict__ ab,
                                                      uint16_t* __restrict__ at) {
  const int b  = blockIdx.z;
  const int s0 = blockIdx.y * 64;
  const int d0 = blockIdx.x * 64;
  __shared__ uint16_t tl[64][80];
  const int tid = threadIdx.x;
#pragma unroll
  for (int i = 0; i < 2; ++i) {
    const int sl = (tid >> 3) + i * 32;
    const int ch = tid & 7;
    const float* src = A + ((size_t)b * SEQ + s0 + sl) * DIM + d0 + ch * 8;
    float4 f0 = *(const float4*)src;
    float4 f1 = *(const float4*)(src + 4);
    u16x8 h;
    h[0] = f2bf(f0.x); h[1] = f2bf(f0.y); h[2] = f2bf(f0.z); h[3] = f2bf(f0.w);
    h[4] = f2bf(f1.x); h[5] = f2bf(f1.y); h[6] = f2bf(f1.z); h[7] = f2bf(f1.w);
    *(u16x8*)&ab[((size_t)b * SEQ + s0 + sl) * DIM + d0 + ch * 8] = h;
    *(u16x8*)&tl[sl][ch * 8] = h;
  }
  __syncthreads();
  const int dl = tid >> 2;
#pragma unroll
  for (int i = 0; i < 2; ++i) {
    const int sc = (tid & 3) + i * 4;
    u16x8 h;
#pragma unroll
    for (int e = 0; e < 8; ++e) h[e] = tl[sc * 8 + e][dl];
    *(u16x8*)&at[((size_t)b * DIM + d0 + dl) * SEQ + s0 + sc * 8] = h;
  }
}

// ---------------------------------------------------------------------------
// Shared GEMM geometry (kernels 2 & 3): BM=BN=128, BK=32, 4 waves (2x2),
// per-wave 64x64 via 2x2 frags of 32x32x16 MFMA (f32x16 acc).
// LDS [2][128][32] bf16 per operand (linear dest for global_load_lds).
// Swizzle: 16B-chunk ^= (row>>1)&3, applied on global SOURCE at staging and
// on ds_read addr (rule #21) -> conflict-free fragment reads.
// 2-phase loop: stage(next) at top, compute cur, one __syncthreads per iter.
// ---------------------------------------------------------------------------

// Kernel 2: P[b][q][t] = m_q*m_t*exp(ab[q]·ab[t])  (bf16)
__global__ __launch_bounds__(256) void scores_kernel(const uint16_t* __restrict__ ab,
                                                     const int* __restrict__ mask,
                                                     uint16_t* __restrict__ P) {
  const int b    = blockIdx.x & 7;
  const int tile = blockIdx.x >> 3;          // 0..63
  const int s0   = (tile >> 3) * 128;
  const int t0   = (tile & 7) * 128;

  const int tid  = threadIdx.x;
  const int lane = tid & 63;
  const int l31  = lane & 31;
  const int lhi  = lane >> 5;                // 0..1
  const int wid  = tid >> 6;
  const int wr   = wid >> 1;                 // 0..1
  const int wc   = wid & 1;                  // 0..1

  __shared__ __align__(16) uint16_t lQ[2][128 * 32];
  __shared__ __align__(16) uint16_t lK[2][128 * 32];
  __shared__ float mrow[128];
  __shared__ float mcol[128];

  if (tid < 128)        mrow[tid]       = (float)mask[b * SEQ + s0 + tid];
  else                  mcol[tid - 128] = (float)mask[b * SEQ + t0 + (tid - 128)];

  const uint16_t* gQ = ab + ((size_t)b * SEQ + s0) * DIM;
  const uint16_t* gK = ab + ((size_t)b * SEQ + t0) * DIM;

  // staging: thread t covers rows (t>>2) and (t>>2)+64, 16B chunk (t&3).
  // source chunk pre-swizzled; (row>>1)&3 identical for both rows (+64).
  const int strow = tid >> 2;
  const int schx  = (((tid & 3) ^ ((tid >> 3) & 3)) << 3);
  const int sdst  = tid * 8;
#define STG(L, G, LDG, buf, k0)                                                \
  { gload16(G + (size_t)strow * (LDG) + (k0) + schx, &L[buf][sdst]);           \
    gload16(G + (size_t)(strow + 64) * (LDG) + (k0) + schx,                    \
            &L[buf][sdst + 2048]); }

  f32x16 acc[2][2];
#pragma unroll
  for (int m = 0; m < 2; ++m)
#pragma unroll
    for (int n = 0; n < 2; ++n)
#pragma unroll
      for (int r = 0; r < 16; ++r) acc[m][n][r] = 0.f;

  // fragment read offsets (elems): row*32 + ((kk*2+lhi)^((row>>1)&3))*8
  int offQ[2][2], offK[2][2];
#pragma unroll
  for (int m = 0; m < 2; ++m) {
    const int rQ = wr * 64 + m * 32 + l31;
    const int rK = wc * 64 + m * 32 + l31;
#pragma unroll
    for (int kk = 0; kk < 2; ++kk) {
      offQ[m][kk] = rQ * 32 + (((kk << 1) + lhi) ^ ((rQ >> 1) & 3)) * 8;
      offK[m][kk] = rK * 32 + (((kk << 1) + lhi) ^ ((rK >> 1) & 3)) * 8;
    }
  }

  STG(lQ, gQ, DIM, 0, 0); STG(lK, gK, DIM, 0, 0);
  __syncthreads();

  const int NT = DIM / 32;                   // 24
  int cur = 0;
  for (int t = 0; t < NT; ++t) {
    const int nx = cur ^ 1;
    if (t + 1 < NT) { STG(lQ, gQ, DIM, nx, (t + 1) * 32); STG(lK, gK, DIM, nx, (t + 1) * 32); }

    bf16x8 qf[2][2], kf[2][2];
#pragma unroll
    for (int m = 0; m < 2; ++m)
#pragma unroll
      for (int kk = 0; kk < 2; ++kk) {
        qf[m][kk] = *(const bf16x8*)&lQ[cur][offQ[m][kk]];
        kf[m][kk] = *(const bf16x8*)&lK[cur][offK[m][kk]];
      }
#pragma unroll
    for (int kk = 0; kk < 2; ++kk)
#pragma unroll
      for (int m = 0; m < 2; ++m)
#pragma unroll
        for (int n = 0; n < 2; ++n)
          acc[m][n] = MFMA32(qf[m][kk], kf[n][kk], acc[m][n]);

    __syncthreads();
    cur ^= 1;
  }

  // Epilogue: e = exp(S)*m_q*m_t, bf16 store (32 lanes x 2B = 64B contig).
  uint16_t* Pb = P + (size_t)b * SEQ * SEQ;
#pragma unroll
  for (int m = 0; m < 2; ++m) {
#pragma unroll
    for (int n = 0; n < 2; ++n) {
      const int cl = wc * 64 + n * 32 + l31;
      const float mc = mcol[cl];
#pragma unroll
      for (int r = 0; r < 16; ++r) {
        const int rl = wr * 64 + m * 32 + (r & 3) + 8 * (r >> 2) + 4 * lhi;
        float e = __expf(acc[m][n][r]) * mrow[rl] * mc;
        Pb[(size_t)(s0 + rl) * SEQ + t0 + cl] = f2bf(e);
      }
    }
  }
}

// Kernel 3: out[b][q][d] = sum_t P[q][t]*at[d][t] / (den_q+eps)
// den via ones-B MFMA: accd[m] row-map matches acc rows (col-independent).
__global__ __launch_bounds__(256) void out_kernel(const uint16_t* __restrict__ P,
                                                  const uint16_t* __restrict__ at,
                                                  float* __restrict__ out) {
  const int b    = blockIdx.x & 7;
  const int tile = blockIdx.x >> 3;          // 0..47
  const int q0   = (tile / 6) * 128;
  const int d0   = (tile % 6) * 128;

  const int tid  = threadIdx.x;
  const int lane = tid & 63;
  const int l31  = lane & 31;
  const int lhi  = lane >> 5;
  const int wid  = tid >> 6;
  const int wr   = wid >> 1;
  const int wc   = wid & 1;

  __shared__ __align__(16) uint16_t lP[2][128 * 32];
  __shared__ __align__(16) uint16_t lV[2][128 * 32];

  const uint16_t* gP = P  + ((size_t)b * SEQ + q0) * SEQ;
  const uint16_t* gV = at + ((size_t)b * DIM + d0) * SEQ;

  const int strow = tid >> 2;
  const int schx  = (((tid & 3) ^ ((tid >> 3) & 3)) << 3);
  const int sdst  = tid * 8;

  f32x16 acc[2][2];
  f32x16 accd[2];
#pragma unroll
  for (int m = 0; m < 2; ++m) {
#pragma unroll
    for (int r = 0; r < 16; ++r) accd[m][r] = 0.f;
#pragma unroll
    for (int n = 0; n < 2; ++n)
#pragma unroll
      for (int r = 0; r < 16; ++r) acc[m][n][r] = 0.f;
  }
  bf16x8 ones;
#pragma unroll
  for (int i = 0; i < 8; ++i) ones[i] = (__bf16)1.0f;

  int offP[2][2], offV[2][2];
#pragma unroll
  for (int m = 0; m < 2; ++m) {
    const int rP = wr * 64 + m * 32 + l31;
    const int rV = wc * 64 + m * 32 + l31;
#pragma unroll
    for (int kk = 0; kk < 2; ++kk) {
      offP[m][kk] = rP * 32 + (((kk << 1) + lhi) ^ ((rP >> 1) & 3)) * 8;
      offV[m][kk] = rV * 32 + (((kk << 1) + lhi) ^ ((rV >> 1) & 3)) * 8;
    }
  }

  STG(lP, gP, SEQ, 0, 0); STG(lV, gV, SEQ, 0, 0);
  __syncthreads();

  const int NT = SEQ / 32;                   // 32
  int cur = 0;
  for (int t = 0; t < NT; ++t) {
    const int nx = cur ^ 1;
    if (t + 1 < NT) { STG(lP, gP, SEQ, nx, (t + 1) * 32); STG(lV, gV, SEQ, nx, (t + 1) * 32); }

    bf16x8 pf[2][2], vf[2][2];
#pragma unroll
    for (int m = 0; m < 2; ++m)
#pragma unroll
      for (int kk = 0; kk < 2; ++kk) {
        pf[m][kk] = *(const bf16x8*)&lP[cur][offP[m][kk]];
        vf[m][kk] = *(const bf16x8*)&lV[cur][offV[m][kk]];
      }
#pragma unroll
    for (int kk = 0; kk < 2; ++kk)
#pragma unroll
      for (int m = 0; m < 2; ++m) {
#pragma unroll
        for (int n = 0; n < 2; ++n)
          acc[m][n] = MFMA32(pf[m][kk], vf[n][kk], acc[m][n]);
        accd[m] = MFMA32(pf[m][kk], ones, accd[m]);
      }

    __syncthreads();
    cur ^= 1;
  }

  float* ob = out + (size_t)b * SEQ * DIM;
#pragma unroll
  for (int m = 0; m < 2; ++m) {
#pragma unroll
    for (int r = 0; r < 16; ++r) {
      const int rl = wr * 64 + m * 32 + (r & 3) + 8 * (r >> 2) + 4 * lhi;
      const float sc = 1.0f / (accd[m][r] + EPS_K);
#pragma unroll
      for (int n = 0; n < 2; ++n) {
        const int d = d0 + wc * 64 + n * 32 + l31;
        ob[(size_t)(q0 + rl) * DIM + d] = acc[m][n][r] * sc;
      }
    }
  }
}
#undef STG

// ---------------------------------------------------------------------------
extern "C" void kernel_launch(void* const* d_in, const int* in_sizes, int n_in,
                              void* d_out, int out_size, void* d_ws, size_t ws_size,
                              hipStream_t stream) {
  (void)in_sizes; (void)n_in; (void)out_size; (void)ws_size;
  const float* A    = (const float*)d_in[0];
  const int*   mask = (const int*)d_in[1];
  float*       out  = (float*)d_out;

  char* ws = (char*)d_ws;
  const size_t NB_AB = (size_t)BATCH * SEQ * DIM * 2;
  const size_t NB_AT = NB_AB;
  uint16_t* ab = (uint16_t*)(ws);
  uint16_t* at = (uint16_t*)(ws + NB_AB);
  uint16_t* P  = (uint16_t*)(ws + NB_AB + NB_AT);

  convert_kernel<<<dim3(DIM / 64, SEQ / 64, BATCH), dim3(256), 0, stream>>>(A, ab, at);
  scores_kernel<<<dim3(64 * BATCH), dim3(256), 0, stream>>>(ab, mask, P);
  out_kernel<<<dim3(48 * BATCH), dim3(256), 0, stream>>>(P, at, out);
}